// Round 7
// baseline (239.307 us; speedup 1.0000x reference)
//
#include <hip/hip_runtime.h>
#include <stdint.h>

// Problem: BahdanauAttention  H=512, L=2, B=64, T=2048
// scores[t,b] = Wo . tanh( enc[t,b,:] @ We^T + comb[b,:] )   (bo dropped: softmax-invariant)
// comb[b,:]   = mean_l(hidden[l,b,:]) @ Wh^T + bh + be
// out[b,t]    = masked softmax over t < enc_len[b]
//
// R7: LDS-A streaming GEMM. Block = one t (64 rows=all b), 256 thr / 4 waves.
// Phase 1: A 64x512 f32 -> bf16 -> LDS (64 KB, XOR-swizzled), burst loads, ONE
// barrier. Phase 2 (barrier-free): waves pair on 32-row halves and split N:
// wave w -> rows [(w>>1)*32,+32), nh chunks (w&1)*4..+4. B frags streamed from
// L2 (packed granules, 3-deep prefetch), af read per-step from LDS (b128).
// acc 32 + bp 48 + af 8 VGPRs -> no remat (R6 failure mode). 2 blocks/CU.
//
// Workspace (1,152 KB):
//   [0, 512K)     : We packed bf16 frag-granules (R6 layout)
//   [512K, 640K)  : comb_t f32 [512 col][64 b]  (transposed)
//   [640K, 1152K) : scores f32 [64][2048]

typedef __attribute__((ext_vector_type(4))) float f32x4;
typedef __attribute__((ext_vector_type(8))) __bf16 bf16x8;
typedef __attribute__((ext_vector_type(8))) unsigned short u16x8;
typedef __attribute__((ext_vector_type(4))) unsigned short u16x4;

__device__ __forceinline__ float fast_tanh(float x) {
  float t = __expf(-2.0f * __builtin_fabsf(x));
  float r = (1.0f - t) * __builtin_amdgcn_rcpf(1.0f + t);
  return __builtin_copysignf(r, x);
}

// ---------------- prep 1: comb_t[o][b] = (mean_l hidden @ Wh^T + bh + be)^T --
__global__ void prep_comb_kernel(const float* __restrict__ hidden,
                                 const float* __restrict__ Wh,
                                 const float* __restrict__ bh,
                                 const float* __restrict__ be,
                                 float* __restrict__ comb_t) {
  __shared__ float hb[512];
  const int b = blockIdx.x, tid = threadIdx.x;  // 512 threads, tid = o
  hb[tid] = 0.5f * (hidden[b * 512 + tid] + hidden[32768 + b * 512 + tid]);
  __syncthreads();
  const f32x4* wr = (const f32x4*)(Wh + tid * 512);
  const f32x4* hv = (const f32x4*)hb;
  float s = 0.f;
  for (int k = 0; k < 128; ++k) {
    f32x4 w = wr[k], x = hv[k];
    s += w.x * x.x + w.y * x.y + w.z * x.z + w.w * x.w;
  }
  comb_t[tid * 64 + b] = s + bh[tid] + be[tid];
}

// ---------------- prep 2: pack We -> bf16 B-fragment granules (R6 layout) ----
// gid granule: lane = gid&63, nt = (gid>>6)&3, kh = (gid>>8)&15, nh = gid>>12.
// col = nh*64 + nt*16 + (lane&15), k = kh*32 + (lane>>4)*8.
__global__ void prep_pack_kernel(const float* __restrict__ We,
                                 unsigned short* __restrict__ wsw) {
  const int gid = blockIdx.x * 256 + threadIdx.x;  // 0..32767
  const int lane = gid & 63;
  const int nt = (gid >> 6) & 3;
  const int kh = (gid >> 8) & 15;
  const int nh = gid >> 12;
  const int col = nh * 64 + nt * 16 + (lane & 15);
  const int k = kh * 32 + (lane >> 4) * 8;
  const float* src = We + col * 512 + k;
  u16x8 p;
#pragma unroll
  for (int e = 0; e < 8; ++e)
    p[e] = __builtin_bit_cast(unsigned short, (__bf16)src[e]);
  *(u16x8*)(wsw + (long)gid * 8) = p;
}

// ---------------- main: LDS-A streaming GEMM + tanh + Wo-dot -----------------
__global__ __launch_bounds__(256, 2) void gemm_score_kernel(
    const float* __restrict__ enc,            // [131072, 512] (row = t*64+b)
    const unsigned short* __restrict__ wsw,   // packed We frags
    const float* __restrict__ comb_t,         // [512][64]
    const float* __restrict__ Wo,             // [512]
    float* __restrict__ scores)               // [64][2048]
{
  // A panel: row r (=b), k-granule g (8 bf16): byte addr =
  //   r*1024 + ((g & ~7) | ((g&7) ^ (r&7)))*16   (+8 for odd half of f32x4 pair)
  __shared__ __align__(16) unsigned char Alds[65536];
  __shared__ float spart[2][64];

  const int tid = threadIdx.x;
  const int lane = tid & 63;
  const int wave = tid >> 6;
  const int l15 = lane & 15;
  const int lq = lane >> 4;
  const int bid = blockIdx.x;          // == t
  const long r0 = (long)bid * 64;

  // ---- phase 1: stage A (64 rows x 512 f32) -> bf16 LDS, swizzled ----
  // 8192 f32x4 granules; idx = round*2048 + j*256 + tid; row = idx>>7, c4 = idx&127.
#pragma unroll
  for (int r = 0; r < 4; ++r) {
    f32x4 buf[8];
#pragma unroll
    for (int j = 0; j < 8; ++j) {
      const int idx = r * 2048 + j * 256 + tid;
      buf[j] = *(const f32x4*)(enc + (r0 + (idx >> 7)) * 512 + (idx & 127) * 4);
    }
#pragma unroll
    for (int j = 0; j < 8; ++j) {
      const int idx = r * 2048 + j * 256 + tid;
      const int row = idx >> 7, c4 = idx & 127;
      const int g = c4 >> 1, half = c4 & 1;
      const int gs = (g & ~7) | ((g & 7) ^ (row & 7));
      u16x4 p;
      p[0] = __builtin_bit_cast(unsigned short, (__bf16)buf[j].x);
      p[1] = __builtin_bit_cast(unsigned short, (__bf16)buf[j].y);
      p[2] = __builtin_bit_cast(unsigned short, (__bf16)buf[j].z);
      p[3] = __builtin_bit_cast(unsigned short, (__bf16)buf[j].w);
      *(u16x4*)(&Alds[row * 1024 + gs * 16 + half * 8]) = p;
    }
  }
  __syncthreads();  // A panel ready; no further barriers until store combine

  // ---- phase 2: wave -> rows [(wave>>1)*32,+32), nh = (wave&1)*4 .. +4 ----
  const int pbase = (wave >> 1) * 32;
  const int nhbase = (wave & 1) * 4;

  // af LDS addr pieces: row_m = pbase + m*16 + l15; per kh granule kh*4+lq.
  const int rowA0 = pbase + l15;
  const int rowA1 = pbase + 16 + l15;
  const unsigned base0 = (unsigned)(rowA0 * 1024);
  const unsigned base1 = (unsigned)(rowA1 * 1024);
  const int sw0 = rowA0 & 7, sw1 = rowA1 & 7;

  float s_acc[2][4];
#pragma unroll
  for (int m = 0; m < 2; ++m)
#pragma unroll
    for (int q = 0; q < 4; ++q) s_acc[m][q] = 0.f;

#pragma unroll 1
  for (int nhi = 0; nhi < 4; ++nhi) {
    const int nh = nhbase + nhi;
    const unsigned short* bb = wsw + (long)nh * 32768 + lane * 8;

    bf16x8 bp0[4], bp1[4], bp2[4];
#pragma unroll
    for (int nt = 0; nt < 4; ++nt) {
      bp0[nt] = *(const bf16x8*)(bb + 0 * 2048 + nt * 512);
      bp1[nt] = *(const bf16x8*)(bb + 1 * 2048 + nt * 512);
      bp2[nt] = *(const bf16x8*)(bb + 2 * 2048 + nt * 512);
    }

    f32x4 acc[2][4];
#pragma unroll
    for (int m = 0; m < 2; ++m)
#pragma unroll
      for (int nt = 0; nt < 4; ++nt) acc[m][nt] = (f32x4){0.f, 0.f, 0.f, 0.f};

#define KH_STEP(kh, BP)                                                         \
  {                                                                             \
    const int gA = (kh) * 4 + lq;                                               \
    bf16x8 af0 = *(const bf16x8*)(&Alds[base0 + (unsigned)(((gA & ~7) | ((gA & 7) ^ sw0)) << 4)]); \
    bf16x8 af1 = *(const bf16x8*)(&Alds[base1 + (unsigned)(((gA & ~7) | ((gA & 7) ^ sw1)) << 4)]); \
    _Pragma("unroll")                                                           \
    for (int nt = 0; nt < 4; ++nt) {                                            \
      acc[0][nt] = __builtin_amdgcn_mfma_f32_16x16x32_bf16(af0, BP[nt], acc[0][nt], 0, 0, 0); \
      acc[1][nt] = __builtin_amdgcn_mfma_f32_16x16x32_bf16(af1, BP[nt], acc[1][nt], 0, 0, 0); \
    }                                                                           \
    if ((kh) + 3 < 16) {                                                        \
      _Pragma("unroll")                                                         \
      for (int nt = 0; nt < 4; ++nt)                                            \
        BP[nt] = *(const bf16x8*)(bb + ((kh) + 3) * 2048 + nt * 512);           \
    }                                                                           \
  }

    KH_STEP(0, bp0)  KH_STEP(1, bp1)  KH_STEP(2, bp2)  KH_STEP(3, bp0)
    KH_STEP(4, bp1)  KH_STEP(5, bp2)  KH_STEP(6, bp0)  KH_STEP(7, bp1)
    KH_STEP(8, bp2)  KH_STEP(9, bp0)  KH_STEP(10, bp1) KH_STEP(11, bp2)
    KH_STEP(12, bp0) KH_STEP(13, bp1) KH_STEP(14, bp2) KH_STEP(15, bp0)
#undef KH_STEP

    // epilogue for this col-chunk: s_acc += tanh(acc + comb)*Wo
    float wo[4];
#pragma unroll
    for (int nt = 0; nt < 4; ++nt) wo[nt] = Wo[nh * 64 + nt * 16 + l15];
    const float* ct = comb_t + (nh * 64 + l15) * 64 + pbase + lq * 4;
#pragma unroll
    for (int m = 0; m < 2; ++m)
#pragma unroll
      for (int q = 0; q < 4; ++q) {
        float sm = 0.f;
#pragma unroll
        for (int nt = 0; nt < 4; ++nt) {
          const float x = acc[m][nt][q] + ct[nt * 1024 + m * 16 + q];
          sm += fast_tanh(x) * wo[nt];
        }
        s_acc[m][q] += sm;
      }
  }

  // ---- reduce over l15, combine wave-pairs via spart, store ----
#pragma unroll
  for (int m = 0; m < 2; ++m)
#pragma unroll
    for (int q = 0; q < 4; ++q) {
      float v = s_acc[m][q];
      v += __shfl_xor(v, 1, 16);
      v += __shfl_xor(v, 2, 16);
      v += __shfl_xor(v, 4, 16);
      v += __shfl_xor(v, 8, 16);
      if (l15 == 0) spart[wave & 1][pbase + m * 16 + lq * 4 + q] = v;
    }
  __syncthreads();
  if (tid < 64)
    scores[(long)tid * 2048 + bid] = spart[0][tid] + spart[1][tid];
}

// ---------------- masked softmax over valid prefix ---------------------------
__global__ void softmax_kernel(const float* __restrict__ scores,
                               const int* __restrict__ enc_len,
                               float* __restrict__ out) {
  const int b = blockIdx.x;
  const int tid = threadIdx.x;  // 256
  const int lane = tid & 63;
  const int wv = tid >> 6;
  __shared__ float red[4];
  const int n = enc_len[b];
  const float* sc = scores + (long)b * 2048;

  float v[8];
  float m = -1e30f;
#pragma unroll
  for (int j = 0; j < 8; ++j) {
    const int t = tid + j * 256;
    v[j] = sc[t];
    if (t < n) m = fmaxf(m, v[j]);
  }
#pragma unroll
  for (int k = 32; k; k >>= 1) m = fmaxf(m, __shfl_xor(m, k, 64));
  if (lane == 0) red[wv] = m;
  __syncthreads();
  m = fmaxf(fmaxf(red[0], red[1]), fmaxf(red[2], red[3]));
  __syncthreads();

  float s = 0.f;
#pragma unroll
  for (int j = 0; j < 8; ++j) {
    const int t = tid + j * 256;
    const float e = (t < n) ? __expf(v[j] - m) : 0.f;
    v[j] = e;
    s += e;
  }
#pragma unroll
  for (int k = 32; k; k >>= 1) s += __shfl_xor(s, k, 64);
  if (lane == 0) red[wv] = s;
  __syncthreads();
  s = red[0] + red[1] + red[2] + red[3];
  const float inv = 1.0f / s;
#pragma unroll
  for (int j = 0; j < 8; ++j) {
    const int t = tid + j * 256;
    out[(long)b * 2048 + t] = v[j] * inv;
  }
}

extern "C" void kernel_launch(void* const* d_in, const int* in_sizes, int n_in,
                              void* d_out, int out_size, void* d_ws, size_t ws_size,
                              hipStream_t stream) {
  const float* hidden = (const float*)d_in[0];   // [2,64,512]
  const float* enc    = (const float*)d_in[1];   // [2048,64,512]
  const int*   enclen = (const int*)d_in[2];     // [64]
  const float* Wh     = (const float*)d_in[3];   // [512,512]
  const float* bh     = (const float*)d_in[4];   // [512]
  const float* We     = (const float*)d_in[5];   // [512,512]
  const float* be     = (const float*)d_in[6];   // [512]
  const float* Wo     = (const float*)d_in[7];   // [512]
  // d_in[8] = bo: softmax-invariant, dropped
  float* out = (float*)d_out;

  uint8_t* ws = (uint8_t*)d_ws;
  unsigned short* wsw = (unsigned short*)ws;             // 512 KB packed We
  float* comb_t = (float*)(ws + 524288);                 // 128 KB [512][64]
  float* scores = (float*)(ws + 524288 + 131072);        // 512 KB

  hipLaunchKernelGGL(prep_comb_kernel, dim3(64), dim3(512), 0, stream,
                     hidden, Wh, bh, be, comb_t);
  hipLaunchKernelGGL(prep_pack_kernel, dim3(128), dim3(256), 0, stream, We, wsw);
  hipLaunchKernelGGL(gemm_score_kernel, dim3(2048), dim3(256), 0, stream,
                     enc, wsw, comb_t, Wo, scores);
  hipLaunchKernelGGL(softmax_kernel, dim3(64), dim3(256), 0, stream,
                     scores, enclen, out);
}